// Round 4
// baseline (68.402 us; speedup 1.0000x reference)
//
#include <hip/hip_runtime.h>

#define T_STEPS 512

__device__ __forceinline__ float exp2_fast(float x) {
#if __has_builtin(__builtin_amdgcn_exp2f)
    return __builtin_amdgcn_exp2f(x);
#else
    return exp2f(x);
#endif
}
__device__ __forceinline__ float rcp_fast(float x) {
#if __has_builtin(__builtin_amdgcn_rcpf)
    return __builtin_amdgcn_rcpf(x);
#else
    return 1.0f / x;
#endif
}

// DPP quad_perm helper (ctrl byte = sel3<<6 | sel2<<4 | sel1<<2 | sel0).
template <int CTRL>
__device__ __forceinline__ float quad_dpp(float v) {
    int r = __builtin_amdgcn_update_dpp(0, __float_as_int(v), CTRL, 0xF, 0xF, true);
    return __int_as_float(r);
}

// FOUR lanes per batch element, quad layout [ (j0,s0), (j0,s1), (j1,s0), (j1,s1) ]:
//   j = hidden unit, s=0 lane computes gates (i, g), s=1 lane computes (f, o).
// Every lane's 2 exp2 + 2 rcp per step are meaningful gate activations, so
// transcendental work per element is unchanged vs the 2-lane layout, but wave
// count doubles to 2048 = 2 waves/SIMD -> the serial chain latency of one wave
// hides under the other. Per step cross-lane: 1 quad_perm to move p=i*g to the
// (f,o) lane, 2 quad_perms to broadcast h0,h1.
// exp2 scale constants are pre-folded into all gate weights/biases.
__global__ __launch_bounds__(64) void lstm_fused4(
    const float* __restrict__ x,      // [B, T]
    const float* __restrict__ W_ih,   // [8]
    const float* __restrict__ W_hh,   // [8, 2]
    const float* __restrict__ b_ih,   // [8]
    const float* __restrict__ b_hh,   // [8]
    const float* __restrict__ fc1_w,  // [128, 2]
    const float* __restrict__ fc1_b,  // [128]
    const float* __restrict__ fc_w,   // [128]
    const float* __restrict__ fc_b,   // [1]
    float* __restrict__ out,          // [B]
    int B)
{
    const int lane = threadIdx.x;
    const int s    = lane & 1;            // 0: (i,g) lane, 1: (f,o) lane
    const int j    = (lane >> 1) & 1;     // hidden unit
    const int e    = blockIdx.x * 16 + (lane >> 2);
    if (e >= B) return;

    const float SIG = -1.4426950408889634f;   // -log2(e)
    const float TNH = -2.8853900817779268f;   // -2*log2(e)

    // Gate rows (PyTorch order i,f,g,o blocks of H=2): row(gate,unit)=2*gate+j.
    const int row_a = 2 * s + j;          // s0 -> i(j), s1 -> f(j)   (sigmoid)
    const int row_b = 4 + 2 * s + j;      // s0 -> g(j), s1 -> o(j)
    const float sc_a = SIG;
    const float sc_b = (s == 0) ? TNH : SIG;  // g is tanh
    const float kb   = (s == 0) ? 2.f : 1.f;  // act_b = kb*rcp(1+E)+mb
    const float mb   = (s == 0) ? -1.f : 0.f;

    const float Aa = W_ih[row_a] * sc_a;
    const float Ba = (b_ih[row_a] + b_hh[row_a]) * sc_a;
    const float wa0 = W_hh[2 * row_a + 0] * sc_a;
    const float wa1 = W_hh[2 * row_a + 1] * sc_a;
    const float Ab = W_ih[row_b] * sc_b;
    const float Bb = (b_ih[row_b] + b_hh[row_b]) * sc_b;
    const float wb0 = W_hh[2 * row_b + 0] * sc_b;
    const float wb1 = W_hh[2 * row_b + 1] * sc_b;

    float h0 = 0.f, h1 = 0.f, c = 0.f;
    const float4* xv = reinterpret_cast<const float4*>(x + (size_t)e * T_STEPS);

    float4 xA = xv[0];
    float4 xB = xv[1];

#pragma unroll 1
    for (int t4 = 0; t4 < T_STEPS / 4; t4 += 2) {
        float4 xC = xv[(t4 + 2) & (T_STEPS / 4 - 1)];
        float4 xD = xv[(t4 + 3) & (T_STEPS / 4 - 1)];

        float xs8[8] = {xA.x, xA.y, xA.z, xA.w, xB.x, xB.y, xB.z, xB.w};
        // Input projections for all 8 steps: off the critical path.
        float qa[8], qb[8];
#pragma unroll
        for (int k = 0; k < 8; ++k) {
            qa[k] = fmaf(xs8[k], Aa, Ba);
            qb[k] = fmaf(xs8[k], Ab, Bb);
        }
#pragma unroll
        for (int k = 0; k < 8; ++k) {
            float za = fmaf(wa1, h1, fmaf(wa0, h0, qa[k]));
            float zb = fmaf(wb1, h1, fmaf(wb0, h0, qb[k]));
            float Ea = exp2_fast(za);
            float Eb = exp2_fast(zb);
            float ra = rcp_fast(1.f + Ea);        // s0: i, s1: f
            float rb = rcp_fast(1.f + Eb);
            float actb = fmaf(kb, rb, mb);        // s0: g(tanh), s1: o(sigmoid)
            float p = ra * actb;                  // s0: i*g (s1: unused)
            float pp = quad_dpp<0xA0>(p);         // lanes {0,1}<-0, {2,3}<-2
            c = fmaf(ra, c, pp);                  // s1: f*c + i*g (s0: garbage, bounded)
            float Ec = exp2_fast(c * TNH);
            float rc = rcp_fast(1.f + Ec);
            float t = fmaf(2.f, rc, -1.f);        // tanh(c)
            float hm = actb * t;                  // s1: o*tanh(c)
            h0 = quad_dpp<0x55>(hm);              // broadcast lane1 (unit0 h)
            h1 = quad_dpp<0xFF>(hm);              // broadcast lane3 (unit1 h)
        }
        xA = xC;
        xB = xD;
    }

    // Head: relu -> fc1(2->128) -> relu -> fc(128->1), split over the 4 quad
    // lanes (32 rows each, rows interleaved for coalesced float2 loads).
    float hr0 = fmaxf(h0, 0.f), hr1 = fmaxf(h1, 0.f);
    float acc = 0.f;
    const float2* w2 = reinterpret_cast<const float2*>(fc1_w);
    const int l4 = lane & 3;
#pragma unroll 4
    for (int m = 0; m < 32; ++m) {
        int r = l4 + 4 * m;
        float2 w = w2[r];
        float v = fmaf(hr1, w.y, fmaf(hr0, w.x, fc1_b[r]));
        acc = fmaf(fmaxf(v, 0.f), fc_w[r], acc);
    }
    acc += quad_dpp<0xB1>(acc);   // + lane^1
    acc += quad_dpp<0x4E>(acc);   // + lane^2
    if (l4 == 0) out[e] = acc + fc_b[0];
}

extern "C" void kernel_launch(void* const* d_in, const int* in_sizes, int n_in,
                              void* d_out, int out_size, void* d_ws, size_t ws_size,
                              hipStream_t stream) {
    const float* x     = (const float*)d_in[0];
    const float* W_ih  = (const float*)d_in[1];
    const float* W_hh  = (const float*)d_in[2];
    const float* b_ih  = (const float*)d_in[3];
    const float* b_hh  = (const float*)d_in[4];
    const float* fc1_w = (const float*)d_in[5];
    const float* fc1_b = (const float*)d_in[6];
    const float* fc_w  = (const float*)d_in[7];
    const float* fc_b  = (const float*)d_in[8];

    int B = in_sizes[0] / T_STEPS;        // 32768
    int grid = (B + 15) / 16;             // 2048 waves = 2 per SIMD
    lstm_fused4<<<grid, 64, 0, stream>>>(x, W_ih, W_hh, b_ih, b_hh,
                                         fc1_w, fc1_b, fc_w, fc_b,
                                         (float*)d_out, B);
}

// Round 5
// 52.856 us; speedup vs baseline: 1.2941x; 1.2941x over previous
//
#include <hip/hip_runtime.h>

#define T_STEPS 512

typedef float v2f __attribute__((ext_vector_type(2)));

__device__ __forceinline__ float exp2_fast(float x) {
#if __has_builtin(__builtin_amdgcn_exp2f)
    return __builtin_amdgcn_exp2f(x);
#else
    return exp2f(x);
#endif
}
__device__ __forceinline__ float rcp_fast(float x) {
#if __has_builtin(__builtin_amdgcn_rcpf)
    return __builtin_amdgcn_rcpf(x);
#else
    return 1.0f / x;
#endif
}
__device__ __forceinline__ v2f fma2(v2f a, v2f b, v2f c) {
    return __builtin_elementwise_fma(a, b, c);
}

// Swap adjacent lanes (lane ^ 1) via DPP quad_perm [1,0,3,2] = 0xB1.
__device__ __forceinline__ float swap_pair(float v) {
    int r = __builtin_amdgcn_update_dpp(0, __float_as_int(v), 0xB1, 0xF, 0xF, true);
    return __int_as_float(r);
}

// Two lanes per batch element (lane j owns hidden unit j). Activation algebra
// in product form to cut transcendentals from 10 to 8 per step:
//   A=e^-zi, B=e^-2zg, F=e^-zf, D=e^-zo, C=e^-2c   (scales folded into weights)
//   i*g        = (1-B) * rcp((1+A)(1+B))
//   c          = rcp(1+F)*c + i*g
//   o*tanh(c)  = (1-C) * rcp((1+D)(1+C))
// z-projections packed as v2f -> v_pk_fma_f32.
__global__ __launch_bounds__(64) void lstm_fused5(
    const float* __restrict__ x,      // [B, T]
    const float* __restrict__ W_ih,   // [8]
    const float* __restrict__ W_hh,   // [8, 2]
    const float* __restrict__ b_ih,   // [8]
    const float* __restrict__ b_hh,   // [8]
    const float* __restrict__ fc1_w,  // [128, 2]
    const float* __restrict__ fc1_b,  // [128]
    const float* __restrict__ fc_w,   // [128]
    const float* __restrict__ fc_b,   // [1]
    float* __restrict__ out,          // [B]
    int B)
{
    const int lane = threadIdx.x;
    const int j    = lane & 1;
    const int e    = blockIdx.x * 32 + (lane >> 1);
    if (e >= B) return;

    const float SIG = -1.4426950408889634f;   // -log2(e)
    const float TNH = -2.8853900817779268f;   // -2*log2(e)

    // Rows (PyTorch order): i=j, f=2+j, g=4+j, o=6+j.
    const int ri = j, rf = 2 + j, rg = 4 + j, ro = 6 + j;
    // Packed weights: .x -> (i or g), .y -> (f or o).
    const v2f Aif = {W_ih[ri] * SIG, W_ih[rf] * SIG};
    const v2f Ago = {W_ih[rg] * TNH, W_ih[ro] * SIG};
    const v2f Bif = {(b_ih[ri] + b_hh[ri]) * SIG, (b_ih[rf] + b_hh[rf]) * SIG};
    const v2f Bgo = {(b_ih[rg] + b_hh[rg]) * TNH, (b_ih[ro] + b_hh[ro]) * SIG};
    const v2f USif = {W_hh[2 * ri + j] * SIG, W_hh[2 * rf + j] * SIG};
    const v2f USgo = {W_hh[2 * rg + j] * TNH, W_hh[2 * ro + j] * SIG};
    const v2f UOif = {W_hh[2 * ri + (j ^ 1)] * SIG, W_hh[2 * rf + (j ^ 1)] * SIG};
    const v2f UOgo = {W_hh[2 * rg + (j ^ 1)] * TNH, W_hh[2 * ro + (j ^ 1)] * SIG};

    float h = 0.f, c = 0.f, ho = 0.f;
    const float4* xv = reinterpret_cast<const float4*>(x + (size_t)e * T_STEPS);

    float4 xA = xv[0];
    float4 xB = xv[1];

#pragma unroll 1
    for (int t4 = 0; t4 < T_STEPS / 4; t4 += 2) {
        float4 xC = xv[(t4 + 2) & (T_STEPS / 4 - 1)];
        float4 xD = xv[(t4 + 3) & (T_STEPS / 4 - 1)];

        float xs8[8] = {xA.x, xA.y, xA.z, xA.w, xB.x, xB.y, xB.z, xB.w};
        // Input projections (off the critical path).
        v2f qif[8], qgo[8];
#pragma unroll
        for (int k = 0; k < 8; ++k) {
            v2f xsv = {xs8[k], xs8[k]};
            qif[k] = fma2(xsv, Aif, Bif);
            qgo[k] = fma2(xsv, Ago, Bgo);
        }
#pragma unroll
        for (int k = 0; k < 8; ++k) {
            v2f hv  = {h, h};
            v2f hov = {ho, ho};
            v2f zif = fma2(hov, UOif, fma2(hv, USif, qif[k]));
            v2f zgo = fma2(hov, UOgo, fma2(hv, USgo, qgo[k]));
            float A  = exp2_fast(zif.x);
            float F  = exp2_fast(zif.y);
            float Bb = exp2_fast(zgo.x);
            float D  = exp2_fast(zgo.y);
            float dA = 1.f + A, dB = 1.f + Bb, dF = 1.f + F, dD = 1.f + D;
            float rAB = rcp_fast(dA * dB);
            float p   = (1.f - Bb) * rAB;          // i*g
            float rF  = rcp_fast(dF);              // f
            c = fmaf(rF, c, p);
            float C  = exp2_fast(c * TNH);
            float dC = 1.f + C;
            float rDC = rcp_fast(dD * dC);
            h  = (1.f - C) * rDC;                  // o*tanh(c)
            ho = swap_pair(h);
        }
        xA = xC;
        xB = xD;
    }

    // Head: relu -> fc1 (2->128) -> relu -> fc (128->1), split across the pair.
    float hr  = fmaxf(h, 0.f);
    float hro = fmaxf(ho, 0.f);
    float h0 = j ? hro : hr;
    float h1 = j ? hr : hro;

    float part = 0.f;
    const float2* w2 = reinterpret_cast<const float2*>(fc1_w);
    int base = j * 64;
#pragma unroll 4
    for (int m = 0; m < 64; ++m) {
        int jj = base + m;
        float2 w = w2[jj];
        float v = fmaf(h1, w.y, fmaf(h0, w.x, fc1_b[jj]));
        part = fmaf(fmaxf(v, 0.f), fc_w[jj], part);
    }
    part += swap_pair(part);
    if (j == 0) out[e] = part + fc_b[0];
}

extern "C" void kernel_launch(void* const* d_in, const int* in_sizes, int n_in,
                              void* d_out, int out_size, void* d_ws, size_t ws_size,
                              hipStream_t stream) {
    const float* x     = (const float*)d_in[0];
    const float* W_ih  = (const float*)d_in[1];
    const float* W_hh  = (const float*)d_in[2];
    const float* b_ih  = (const float*)d_in[3];
    const float* b_hh  = (const float*)d_in[4];
    const float* fc1_w = (const float*)d_in[5];
    const float* fc1_b = (const float*)d_in[6];
    const float* fc_w  = (const float*)d_in[7];
    const float* fc_b  = (const float*)d_in[8];

    int B = in_sizes[0] / T_STEPS;        // 32768
    int grid = (B + 31) / 32;             // 1024 waves = 1 per SIMD
    lstm_fused5<<<grid, 64, 0, stream>>>(x, W_ih, W_hh, b_ih, b_hh,
                                         fc1_w, fc1_b, fc_w, fc_b,
                                         (float*)d_out, B);
}